// Round 5
// baseline (5071.897 us; speedup 1.0000x reference)
//
#include <hip/hip_runtime.h>
#include <math.h>

#define NB 2048
#define WD 128
#define TD 300
#define TP 320
#define NM 24
#define NJ 48
#define NJP 64
#define NL 6
#define NCOL 38400
#define WSCALE 1024.0f

typedef _Float16 half_t;
typedef _Float16 h8 __attribute__((ext_vector_type(8)));
typedef float f4 __attribute__((ext_vector_type(4)));

#define MFMA(a,b,c) __builtin_amdgcn_mfma_f32_16x16x32_f16(a,b,c,0,0,0)

__device__ __forceinline__ float gelu_f(float v){
    return 0.5f * v * (1.0f + erff(v * 0.70710678118654752f));
}

// ---------------- DFT basis tables (fp16) ----------------
__global__ __launch_bounds__(256) void k_tables(half_t* __restrict__ Fth, half_t* __restrict__ Gt){
    int idx = blockIdx.x*256 + threadIdx.x;
    const float w0 = 6.28318530717958647692f / 300.0f;
    if (idx < NJ*TP) {
        int j = idx / TP, t = idx - j*TP;
        int m = j >> 1;
        float v = 0.0f;
        if (t < TD) {
            int r = (m*t) % TD;
            float ang = (float)r * w0;
            v = (j & 1) ? -sinf(ang) : cosf(ang);
        }
        Fth[idx] = (half_t)v;
    }
    if (idx < TP*NJP) {
        int t = idx / NJP, j = idx - t*NJP;
        float v = 0.0f;
        if (j < NJ) {
            int m = j >> 1;
            int r = (m * (t % TD)) % TD;
            float ang = (float)r * w0;
            float s = (m == 0) ? (1.0f/300.0f) : (2.0f/300.0f);
            if (j & 1) v = (m == 0) ? 0.0f : -s*sinf(ang);
            else       v = s*cosf(ang);
        }
        Gt[idx] = (half_t)v;
    }
}

// ---------------- expanded complex weights ----------------
__global__ __launch_bounds__(256) void k_wx(const float* __restrict__ wr, const float* __restrict__ wi,
                                            half_t* __restrict__ Wxh){
    long idx = (long)blockIdx.x*256 + threadIdx.x;
    if (idx >= (long)NL*NM*256*256) return;
    int k = (int)(idx & 255), n = (int)((idx >> 8) & 255);
    int lm = (int)(idx >> 16);
    int l = lm / NM, m = lm - l*NM;
    int i = k & 127, o = n & 127;
    long src = (((long)(l*WD + i))*WD + o)*NM + m;
    float v;
    if (n < 128) v = (k < 128) ? wr[src] : -wi[src];
    else         v = (k < 128) ? wi[src] :  wr[src];
    Wxh[idx] = (half_t)(v * WSCALE);
}

__global__ __launch_bounds__(256) void k_w3t(const float* __restrict__ w3, half_t* __restrict__ w3t){
    int idx = blockIdx.x*256 + threadIdx.x;
    if (idx >= NCOL*WD) return;
    int k = idx & 127, col = idx >> 7;
    w3t[idx] = (half_t)w3[k*NCOL + col];
}

__global__ __launch_bounds__(256) void k_cwh(const float* __restrict__ cw, half_t* __restrict__ cwh){
    int idx = blockIdx.x*256 + threadIdx.x;
    if (idx >= NL*WD*WD) return;
    cwh[idx] = (half_t)cw[idx];
}

__global__ __launch_bounds__(256) void k_w1h(const float* __restrict__ w1, half_t* __restrict__ w1h){
    int idx = blockIdx.x*256 + threadIdx.x;
    if (idx >= 64*WD) return;
    w1h[idx] = (half_t)w1[idx];
}

// ---------------- encoder ----------------
__global__ __launch_bounds__(256) void k_enc1(const float* __restrict__ p, const float* __restrict__ w1,
                                              const float* __restrict__ b1, float* __restrict__ h1){
    int idx = blockIdx.x*256 + threadIdx.x;
    int b = idx >> 7, k = idx & 127;
    float acc = b1[k];
    #pragma unroll
    for (int j = 0; j < 5; j++) acc += p[b*5+j] * w1[j*WD+k];
    h1[idx] = gelu_f(acc);
}

__global__ __launch_bounds__(256) void k_enc2(const float* __restrict__ h1, const float* __restrict__ w2,
                                              const float* __restrict__ b2, half_t* __restrict__ h2h){
    int idx = blockIdx.x*256 + threadIdx.x;
    int b = idx >> 7, k = idx & 127;
    const float* row = h1 + b*WD;
    float acc = b2[k];
    for (int j = 0; j < WD; j += 4) {
        float4 h4 = *(const float4*)(row + j);
        acc += h4.x * w2[(j+0)*WD+k] + h4.y * w2[(j+1)*WD+k]
             + h4.z * w2[(j+2)*WD+k] + h4.w * w2[(j+3)*WD+k];
    }
    h2h[idx] = (half_t)gelu_f(acc);
}

// ---------------- enc3 MFMA: writes x fp32 only (coalesced) ----------------
__global__ __launch_bounds__(256) void k_enc3(const half_t* __restrict__ h2h, const half_t* __restrict__ w3t,
        const float* __restrict__ b3, float* __restrict__ x){
    int tid = threadIdx.x;
    int lane = tid & 63, w = tid >> 6;
    int wr = w >> 1, wc = w & 1;
    int c0 = blockIdx.x * 128;
    int b0 = blockIdx.y * 64;
    int ln = lane & 15, lk = lane >> 4;
    f4 zz = {0.f,0.f,0.f,0.f};
    f4 acc[2][4];
    #pragma unroll
    for (int i = 0; i < 2; i++) for (int j = 0; j < 4; j++) acc[i][j] = zz;
    const half_t* ap = h2h + (long)(b0 + wr*32 + ln)*WD + lk*8;
    const half_t* bp = w3t + (long)(c0 + wc*64 + ln)*WD + lk*8;
    #pragma unroll
    for (int ks = 0; ks < 4; ks++) {
        h8 a0 = *(const h8*)(ap + ks*32);
        h8 a1 = *(const h8*)(ap + 16*WD + ks*32);
        #pragma unroll
        for (int bt = 0; bt < 4; bt++) {
            h8 bf = *(const h8*)(bp + bt*16*WD + ks*32);
            acc[0][bt] = MFMA(a0, bf, acc[0][bt]);
            acc[1][bt] = MFMA(a1, bf, acc[1][bt]);
        }
    }
    #pragma unroll
    for (int at = 0; at < 2; at++)
    #pragma unroll
    for (int bt = 0; bt < 4; bt++) {
        int col = c0 + wc*64 + bt*16 + ln;
        float bias = b3[col];
        #pragma unroll
        for (int r = 0; r < 4; r++) {
            int b = b0 + wr*32 + at*16 + lk*4 + r;
            x[(long)b*NCOL + col] = acc[at][bt][r] + bias;
        }
    }
}

// ---------------- transpose x[b][c][t] fp32 -> xt[b][t][c] fp16, via LDS ----------------
__global__ __launch_bounds__(256) void k_tr(const float* __restrict__ x, half_t* __restrict__ xt){
    __shared__ half_t tl[WD*65];   // [c][t] pad 65
    int tid = threadIdx.x;
    int t0 = blockIdx.x * 64;
    long b = blockIdx.y;
    {
        int c = tid >> 1, th = tid & 1;
        const float* xp = x + b*NCOL + (long)c*TD + t0 + th*32;
        half_t* dst = &tl[c*65 + th*32];
        #pragma unroll
        for (int i = 0; i < 8; i++) {
            int t = t0 + th*32 + i*4;
            float4 v;
            if (t + 3 < TD) v = *(const float4*)(xp + i*4);
            else v = make_float4((t<TD)?xp[i*4]:0.f, (t+1<TD)?xp[i*4+1]:0.f,
                                 (t+2<TD)?xp[i*4+2]:0.f, (t+3<TD)?xp[i*4+3]:0.f);
            dst[i*4+0]=(half_t)v.x; dst[i*4+1]=(half_t)v.y;
            dst[i*4+2]=(half_t)v.z; dst[i*4+3]=(half_t)v.w;
        }
    }
    __syncthreads();
    {
        int lane = tid & 63, w = tid >> 6;
        const half_t* src = &tl[w*32*65 + lane];
        h8 v[4];
        #pragma unroll
        for (int k2 = 0; k2 < 4; k2++)
            #pragma unroll
            for (int e = 0; e < 8; e++)
                v[k2][e] = src[(k2*8 + e)*65];
        half_t* op = xt + (b*TP + t0 + lane)*WD + w*32;
        *(h8*)(op) = v[0]; *(h8*)(op+8) = v[1]; *(h8*)(op+16) = v[2]; *(h8*)(op+24) = v[3];
    }
}

// ---------------- rfft MFMA: reads fp32 x, converts in-register ----------------
__global__ __launch_bounds__(256) void k_rfft(const float* __restrict__ x,
        const half_t* __restrict__ Fth, half_t* __restrict__ S, int CB){
    int tid = threadIdx.x;
    int lane = tid & 63, w = tid >> 6;
    int ln = lane & 15, lk = lane >> 4;
    long r0 = (long)blockIdx.x*128 + w*32;
    f4 zz = {0.f,0.f,0.f,0.f};
    f4 acc[2][3];
    #pragma unroll
    for (int i = 0; i < 2; i++) for (int j = 0; j < 3; j++) acc[i][j] = zz;
    const half_t* fpB = Fth + ln*TP + lk*8;
    #pragma unroll
    for (int ks = 0; ks < 9; ks++) {
        int kb = ks*32 + lk*8;
        h8 a[2];
        #pragma unroll
        for (int at = 0; at < 2; at++) {
            const float* xp = x + (r0 + at*16 + ln)*TD + kb;
            float4 v0 = *(const float4*)(xp);
            float4 v1 = *(const float4*)(xp + 4);
            a[at][0]=(half_t)v0.x; a[at][1]=(half_t)v0.y; a[at][2]=(half_t)v0.z; a[at][3]=(half_t)v0.w;
            a[at][4]=(half_t)v1.x; a[at][5]=(half_t)v1.y; a[at][6]=(half_t)v1.z; a[at][7]=(half_t)v1.w;
        }
        #pragma unroll
        for (int jt = 0; jt < 3; jt++) {
            h8 bf = *(const h8*)(fpB + jt*16*TP + ks*32);
            acc[0][jt] = MFMA(a[0], bf, acc[0][jt]);
            acc[1][jt] = MFMA(a[1], bf, acc[1][jt]);
        }
    }
    {   // K tail t=288..299, mask t>=300
        int kb = 288 + lk*8;
        h8 a[2];
        #pragma unroll
        for (int at = 0; at < 2; at++) {
            const float* xp = x + (r0 + at*16 + ln)*TD;
            #pragma unroll
            for (int e = 0; e < 8; e++) {
                int k = kb + e;
                a[at][e] = (k < TD) ? (half_t)xp[k] : (half_t)0.0f;
            }
        }
        #pragma unroll
        for (int jt = 0; jt < 3; jt++) {
            h8 bf = *(const h8*)(fpB + jt*16*TP + 288);
            acc[0][jt] = MFMA(a[0], bf, acc[0][jt]);
            acc[1][jt] = MFMA(a[1], bf, acc[1][jt]);
        }
    }
    #pragma unroll
    for (int at = 0; at < 2; at++)
    #pragma unroll
    for (int jt = 0; jt < 3; jt++) {
        int j = jt*16 + ln;
        int m = j >> 1, ri = j & 1;
        #pragma unroll
        for (int r = 0; r < 4; r++) {
            long row = r0 + at*16 + lk*4 + r;
            int b = (int)(row >> 7), c = (int)(row & 127);
            S[((long)m*CB + b)*256 + ri*128 + c] = (half_t)acc[at][jt][r];
        }
    }
}

// ---------------- mix MFMA: per mode, [CB x 256] @ [256 x 256] ----------------
__global__ __launch_bounds__(256) void k_mix(const half_t* __restrict__ S, const half_t* __restrict__ Wxh,
        half_t* __restrict__ Yh, int layer, int CB){
    int tid = threadIdx.x;
    int lane = tid & 63, w = tid >> 6;
    int wr = w >> 1, wc = w & 1;
    int ln = lane & 15, lk = lane >> 4;
    int m = blockIdx.z;
    int b0 = blockIdx.x * 64;
    int n0 = blockIdx.y * 128;
    f4 zz = {0.f,0.f,0.f,0.f};
    f4 acc[2][4];
    #pragma unroll
    for (int i = 0; i < 2; i++) for (int j = 0; j < 4; j++) acc[i][j] = zz;
    const half_t* ap = S + ((long)m*CB + b0 + wr*32 + ln)*256 + lk*8;
    const half_t* bp = Wxh + (((long)(layer*NM + m))*256 + n0 + wc*64 + ln)*256 + lk*8;
    #pragma unroll
    for (int ks = 0; ks < 8; ks++) {
        h8 a0 = *(const h8*)(ap + ks*32);
        h8 a1 = *(const h8*)(ap + 16*256 + ks*32);
        #pragma unroll
        for (int bt = 0; bt < 4; bt++) {
            h8 bf = *(const h8*)(bp + bt*16*256 + ks*32);
            acc[0][bt] = MFMA(a0, bf, acc[0][bt]);
            acc[1][bt] = MFMA(a1, bf, acc[1][bt]);
        }
    }
    const float inv = 1.0f / WSCALE;
    #pragma unroll
    for (int at = 0; at < 2; at++)
    #pragma unroll
    for (int bt = 0; bt < 4; bt++) {
        int n = n0 + wc*64 + bt*16 + ln;
        int o = n & 127, ri = n >> 7;
        #pragma unroll
        for (int r = 0; r < 4; r++) {
            int b = b0 + wr*32 + at*16 + lk*4 + r;
            Yh[((long)b*WD + o)*NJP + 2*m + ri] = (half_t)(acc[at][bt][r] * inv);
        }
    }
}

// ---------------- fused irfft + conv + gelu + residual ----------------
// GEMM K=192: A=[cwh|Yh] rows o, B=[xt|Gt] rows t. Epilogue LDS-staged, coalesced.
__global__ __launch_bounds__(256) void k_fuse(const half_t* __restrict__ Yh, const half_t* __restrict__ Gt,
        const half_t* __restrict__ cwh, half_t* __restrict__ xt, const float* __restrict__ convb,
        float* __restrict__ x, int layer){
    __shared__ float gl[64*133];   // [t][o] pad 133
    int tid = threadIdx.x;
    int lane = tid & 63, w = tid >> 6;
    int wo = w * 32;
    int ln = lane & 15, lk = lane >> 4;
    int t0 = blockIdx.x * 64;
    long b = blockIdx.y;
    f4 zz = {0.f,0.f,0.f,0.f};
    f4 acc[2][4];
    #pragma unroll
    for (int i = 0; i < 2; i++) for (int j = 0; j < 4; j++) acc[i][j] = zz;
    // conv region: K = c 0..127
    const half_t* ap = cwh + ((long)layer*WD + wo + ln)*WD + lk*8;
    const half_t* bp = xt + (b*TP + t0 + ln)*WD + lk*8;
    #pragma unroll
    for (int ks = 0; ks < 4; ks++) {
        h8 a0 = *(const h8*)(ap + ks*32);
        h8 a1 = *(const h8*)(ap + 16*WD + ks*32);
        #pragma unroll
        for (int bt = 0; bt < 4; bt++) {
            h8 bf = *(const h8*)(bp + bt*16*WD + ks*32);
            acc[0][bt] = MFMA(a0, bf, acc[0][bt]);
            acc[1][bt] = MFMA(a1, bf, acc[1][bt]);
        }
    }
    // irfft region: K = j 0..63 (Yh j>=48 finite garbage x Gt zeros -> 0)
    const half_t* ap2 = Yh + (b*WD + wo + ln)*NJP + lk*8;
    const half_t* bp2 = Gt + (long)(t0 + ln)*NJP + lk*8;
    #pragma unroll
    for (int ks = 0; ks < 2; ks++) {
        h8 a0 = *(const h8*)(ap2 + ks*32);
        h8 a1 = *(const h8*)(ap2 + 16*NJP + ks*32);
        #pragma unroll
        for (int bt = 0; bt < 4; bt++) {
            h8 bf = *(const h8*)(bp2 + bt*16*NJP + ks*32);
            acc[0][bt] = MFMA(a0, bf, acc[0][bt]);
            acc[1][bt] = MFMA(a1, bf, acc[1][bt]);
        }
    }
    // stage gelu(acc + bias) into LDS [t][o]
    #pragma unroll
    for (int at = 0; at < 2; at++) {
        int obase = wo + at*16 + lk*4;
        float cb0 = convb[layer*WD + obase];
        float cb1 = convb[layer*WD + obase + 1];
        float cb2 = convb[layer*WD + obase + 2];
        float cb3 = convb[layer*WD + obase + 3];
        #pragma unroll
        for (int bt = 0; bt < 4; bt++) {
            float* g = &gl[(bt*16 + ln)*133 + obase];
            g[0] = gelu_f(acc[at][bt][0] + cb0);
            g[1] = gelu_f(acc[at][bt][1] + cb1);
            g[2] = gelu_f(acc[at][bt][2] + cb2);
            g[3] = gelu_f(acc[at][bt][3] + cb3);
        }
    }
    __syncthreads();
    // phase A: coalesced fp32 x RMW; write x_new back into LDS
    {
        int o = tid >> 1, th = tid & 1;
        int tb = th*32;
        float* xp = x + b*NCOL + (long)o*TD + t0 + tb;
        #pragma unroll
        for (int i = 0; i < 32; i += 4) {
            int t = t0 + tb + i;
            if (t + 3 < TD) {
                float4 xv = *(const float4*)(xp + i);
                float n0 = gl[(tb+i+0)*133 + o] + xv.x;
                float n1 = gl[(tb+i+1)*133 + o] + xv.y;
                float n2 = gl[(tb+i+2)*133 + o] + xv.z;
                float n3 = gl[(tb+i+3)*133 + o] + xv.w;
                *(float4*)(xp + i) = make_float4(n0, n1, n2, n3);
                gl[(tb+i+0)*133 + o] = n0;
                gl[(tb+i+1)*133 + o] = n1;
                gl[(tb+i+2)*133 + o] = n2;
                gl[(tb+i+3)*133 + o] = n3;
            } else {
                #pragma unroll
                for (int e = 0; e < 4; e++) {
                    if (t + e < TD) {
                        float nv = gl[(tb+i+e)*133 + o] + xp[i+e];
                        xp[i+e] = nv;
                        gl[(tb+i+e)*133 + o] = nv;
                    }
                }
            }
        }
    }
    __syncthreads();
    // phase B: coalesced xt write (fp16 of x_new; pad t rows get finite values)
    {
        const float* gr = &gl[lane*133 + wo];
        h8 v[4];
        #pragma unroll
        for (int k2 = 0; k2 < 4; k2++)
            #pragma unroll
            for (int e = 0; e < 8; e++)
                v[k2][e] = (half_t)gr[k2*8 + e];
        half_t* op = xt + (b*TP + t0 + lane)*WD + wo;
        *(h8*)(op) = v[0]; *(h8*)(op+8) = v[1]; *(h8*)(op+16) = v[2]; *(h8*)(op+24) = v[3];
    }
}

// ---------------- output projection MFMA ----------------
__global__ __launch_bounds__(256) void k_out(const half_t* __restrict__ xt, const half_t* __restrict__ w1h,
        const float* __restrict__ b1, const float* __restrict__ w2, const float* __restrict__ b2,
        float* __restrict__ out){
    __shared__ float gl[64*68];   // [t][o] padded
    __shared__ float w2l[192];
    int tid = threadIdx.x;
    int lane = tid & 63, w = tid >> 6;
    int mo = (w >> 1)*32, mt = (w & 1)*32;
    int ln = lane & 15, lk = lane >> 4;
    int t0 = blockIdx.x * 64;
    long b = blockIdx.y;
    f4 zz = {0.f,0.f,0.f,0.f};
    f4 acc[2][2];
    #pragma unroll
    for (int i = 0; i < 2; i++) for (int j = 0; j < 2; j++) acc[i][j] = zz;
    const half_t* ap = w1h + (long)(mo + ln)*WD + lk*8;
    const half_t* bp = xt + (b*TP + t0 + mt + ln)*WD + lk*8;
    #pragma unroll
    for (int ks = 0; ks < 4; ks++) {
        h8 a0 = *(const h8*)(ap + ks*32);
        h8 a1 = *(const h8*)(ap + 16*WD + ks*32);
        h8 b0f = *(const h8*)(bp + ks*32);
        h8 b1f = *(const h8*)(bp + 16*WD + ks*32);
        acc[0][0] = MFMA(a0, b0f, acc[0][0]);
        acc[0][1] = MFMA(a0, b1f, acc[0][1]);
        acc[1][0] = MFMA(a1, b0f, acc[1][0]);
        acc[1][1] = MFMA(a1, b1f, acc[1][1]);
    }
    if (tid < 192) w2l[tid] = w2[tid];
    #pragma unroll
    for (int at = 0; at < 2; at++)
    #pragma unroll
    for (int bt = 0; bt < 2; bt++) {
        int tl = mt + bt*16 + ln;
        int obase = mo + at*16 + lk*4;
        #pragma unroll
        for (int r = 0; r < 4; r++) {
            int o = obase + r;
            gl[tl*68 + o] = gelu_f(acc[at][bt][r] + b1[o]);
        }
    }
    __syncthreads();
    int t = tid & 63, q = tid >> 6;
    int tg = t0 + t;
    if (q < 3 && tg < TD) {
        float s = b2[q];
        const float* gr = &gl[t*68];
        const float* wr = &w2l[q*64];
        #pragma unroll
        for (int o = 0; o < 64; o += 4) {
            s += wr[o]*gr[o] + wr[o+1]*gr[o+1] + wr[o+2]*gr[o+2] + wr[o+3]*gr[o+3];
        }
        out[((long)b*TD + tg)*3 + q] = s;
    }
}

extern "C" void kernel_launch(void* const* d_in, const int* in_sizes, int n_in,
                              void* d_out, int out_size, void* d_ws, size_t ws_size,
                              hipStream_t stream) {
    const float* params = (const float*)d_in[0];
    const float* enc_w1 = (const float*)d_in[1];
    const float* enc_b1 = (const float*)d_in[2];
    const float* enc_w2 = (const float*)d_in[3];
    const float* enc_b2 = (const float*)d_in[4];
    const float* enc_w3 = (const float*)d_in[5];
    const float* enc_b3 = (const float*)d_in[6];
    const float* spec_wr = (const float*)d_in[7];
    const float* spec_wi = (const float*)d_in[8];
    const float* conv_w  = (const float*)d_in[9];
    const float* conv_b  = (const float*)d_in[10];
    const float* out_w1  = (const float*)d_in[11];
    const float* out_b1  = (const float*)d_in[12];
    const float* out_w2  = (const float*)d_in[13];
    const float* out_b2  = (const float*)d_in[14];
    float* outp = (float*)d_out;

    const long szWxh = (long)NL*NM*256*256*2;
    const long szW3t = (long)NCOL*WD*2;
    const long szCwh = (long)NL*WD*WD*2;
    const long szW1h = (long)64*WD*2;
    const long szFth = (long)NJ*TP*2;
    const long szGt  = (long)TP*NJP*2;
    const long fixedB = szWxh + szW3t + szCwh + szW1h + szFth + szGt;
    // per-sample bytes: x + xt + S + Yh + h1 + h2h
    const long perCB = (long)NCOL*4 + (long)TP*WD*2 + (long)NM*256*2 + (long)WD*NJP*2 + WD*4 + WD*2;

    // CB=512: chunk working set ~165 MB, fits the 256 MB Infinity Cache
    long CB = 512;
    while (CB > 64 && fixedB + CB*perCB > (long)ws_size) CB >>= 1;
    int nchunk = (int)(NB / CB);

    char* p = (char*)d_ws;
    half_t* Wxh = (half_t*)p; p += szWxh;
    half_t* w3t = (half_t*)p; p += szW3t;
    half_t* cwh = (half_t*)p; p += szCwh;
    half_t* w1h = (half_t*)p; p += szW1h;
    half_t* Fth = (half_t*)p; p += szFth;
    half_t* Gt  = (half_t*)p; p += szGt;
    float*  x   = (float*)p;  p += CB*(long)NCOL*4;
    half_t* xt  = (half_t*)p; p += CB*(long)TP*WD*2;
    half_t* S   = (half_t*)p; p += CB*(long)NM*256*2;
    half_t* Yh  = (half_t*)p; p += CB*(long)WD*NJP*2;
    float*  h1  = (float*)p;  p += CB*(long)WD*4;
    half_t* h2h = (half_t*)p; p += CB*(long)WD*2;

    k_tables<<<80, 256, 0, stream>>>(Fth, Gt);
    k_wx<<<36864, 256, 0, stream>>>(spec_wr, spec_wi, Wxh);
    k_w3t<<<19200, 256, 0, stream>>>(enc_w3, w3t);
    k_cwh<<<384, 256, 0, stream>>>(conv_w, cwh);
    k_w1h<<<32, 256, 0, stream>>>(out_w1, w1h);

    for (int ch = 0; ch < nchunk; ch++) {
        const float* pch = params + (long)ch*CB*5;
        float* outch = outp + (long)ch*CB*TD*3;
        k_enc1<<<(int)(CB*WD/256), 256, 0, stream>>>(pch, enc_w1, enc_b1, h1);
        k_enc2<<<(int)(CB*WD/256), 256, 0, stream>>>(h1, enc_w2, enc_b2, h2h);
        k_enc3<<<dim3(NCOL/128, (int)(CB/64)), 256, 0, stream>>>(h2h, w3t, enc_b3, x);
        k_tr<<<dim3(TP/64, (int)CB), 256, 0, stream>>>(x, xt);
        for (int l = 0; l < NL; l++) {
            k_rfft<<<(int)CB, 256, 0, stream>>>(x, Fth, S, (int)CB);
            k_mix<<<dim3((int)(CB/64), 2, NM), 256, 0, stream>>>(S, Wxh, Yh, l, (int)CB);
            k_fuse<<<dim3(TP/64, (int)CB), 256, 0, stream>>>(Yh, Gt, cwh, xt, conv_b, x, l);
        }
        k_out<<<dim3(TP/64, (int)CB), 256, 0, stream>>>(xt, w1h, out_b1, out_w2, out_b2, outch);
    }
}

// Round 6
// 3598.688 us; speedup vs baseline: 1.4094x; 1.4094x over previous
//
#include <hip/hip_runtime.h>
#include <math.h>

#define NB 2048
#define WD 128
#define TD 300
#define TP 320
#define NM 24
#define NJ 48
#define NJP 64
#define NL 6
#define NCOL 38400
#define WSCALE 1024.0f

typedef _Float16 half_t;
typedef _Float16 h8 __attribute__((ext_vector_type(8)));
typedef float f4 __attribute__((ext_vector_type(4)));

#define MFMA(a,b,c) __builtin_amdgcn_mfma_f32_16x16x32_f16(a,b,c,0,0,0)

__device__ __forceinline__ float gelu_f(float v){
    return 0.5f * v * (1.0f + erff(v * 0.70710678118654752f));
}

// ---------------- DFT basis tables (fp16) ----------------
__global__ __launch_bounds__(256) void k_tables(half_t* __restrict__ Fth, half_t* __restrict__ Gt){
    int idx = blockIdx.x*256 + threadIdx.x;
    const float w0 = 6.28318530717958647692f / 300.0f;
    if (idx < NJ*TP) {
        int j = idx / TP, t = idx - j*TP;
        int m = j >> 1;
        float v = 0.0f;
        if (t < TD) {
            int r = (m*t) % TD;
            float ang = (float)r * w0;
            v = (j & 1) ? -sinf(ang) : cosf(ang);
        }
        Fth[idx] = (half_t)v;
    }
    if (idx < TP*NJP) {
        int t = idx / NJP, j = idx - t*NJP;
        float v = 0.0f;
        if (j < NJ) {
            int m = j >> 1;
            int r = (m * (t % TD)) % TD;
            float ang = (float)r * w0;
            float s = (m == 0) ? (1.0f/300.0f) : (2.0f/300.0f);
            if (j & 1) v = (m == 0) ? 0.0f : -s*sinf(ang);
            else       v = s*cosf(ang);
        }
        Gt[idx] = (half_t)v;
    }
}

// ---------------- expanded complex weights ----------------
__global__ __launch_bounds__(256) void k_wx(const float* __restrict__ wr, const float* __restrict__ wi,
                                            half_t* __restrict__ Wxh){
    long idx = (long)blockIdx.x*256 + threadIdx.x;
    if (idx >= (long)NL*NM*256*256) return;
    int k = (int)(idx & 255), n = (int)((idx >> 8) & 255);
    int lm = (int)(idx >> 16);
    int l = lm / NM, m = lm - l*NM;
    int i = k & 127, o = n & 127;
    long src = (((long)(l*WD + i))*WD + o)*NM + m;
    float v;
    if (n < 128) v = (k < 128) ? wr[src] : -wi[src];
    else         v = (k < 128) ? wi[src] :  wr[src];
    Wxh[idx] = (half_t)(v * WSCALE);
}

__global__ __launch_bounds__(256) void k_w3t(const float* __restrict__ w3, half_t* __restrict__ w3t){
    int idx = blockIdx.x*256 + threadIdx.x;
    if (idx >= NCOL*WD) return;
    int k = idx & 127, col = idx >> 7;
    w3t[idx] = (half_t)w3[k*NCOL + col];
}

__global__ __launch_bounds__(256) void k_cwh(const float* __restrict__ cw, half_t* __restrict__ cwh){
    int idx = blockIdx.x*256 + threadIdx.x;
    if (idx >= NL*WD*WD) return;
    cwh[idx] = (half_t)cw[idx];
}

__global__ __launch_bounds__(256) void k_w1h(const float* __restrict__ w1, half_t* __restrict__ w1h){
    int idx = blockIdx.x*256 + threadIdx.x;
    if (idx >= 64*WD) return;
    w1h[idx] = (half_t)w1[idx];
}

// ---------------- encoder ----------------
__global__ __launch_bounds__(256) void k_enc1(const float* __restrict__ p, const float* __restrict__ w1,
                                              const float* __restrict__ b1, float* __restrict__ h1){
    int idx = blockIdx.x*256 + threadIdx.x;
    int b = idx >> 7, k = idx & 127;
    float acc = b1[k];
    #pragma unroll
    for (int j = 0; j < 5; j++) acc += p[b*5+j] * w1[j*WD+k];
    h1[idx] = gelu_f(acc);
}

__global__ __launch_bounds__(256) void k_enc2(const float* __restrict__ h1, const float* __restrict__ w2,
                                              const float* __restrict__ b2, half_t* __restrict__ h2h){
    int idx = blockIdx.x*256 + threadIdx.x;
    int b = idx >> 7, k = idx & 127;
    const float* row = h1 + b*WD;
    float acc = b2[k];
    for (int j = 0; j < WD; j += 4) {
        float4 h4 = *(const float4*)(row + j);
        acc += h4.x * w2[(j+0)*WD+k] + h4.y * w2[(j+1)*WD+k]
             + h4.z * w2[(j+2)*WD+k] + h4.w * w2[(j+3)*WD+k];
    }
    h2h[idx] = (half_t)gelu_f(acc);
}

// ---------------- enc3 MFMA: writes x fp32 (coalesced); x is only used by k_tr2 ----------------
__global__ __launch_bounds__(256) void k_enc3(const half_t* __restrict__ h2h, const half_t* __restrict__ w3t,
        const float* __restrict__ b3, float* __restrict__ x){
    int tid = threadIdx.x;
    int lane = tid & 63, w = tid >> 6;
    int wr = w >> 1, wc = w & 1;
    int c0 = blockIdx.x * 128;
    int b0 = blockIdx.y * 64;
    int ln = lane & 15, lk = lane >> 4;
    f4 zz = {0.f,0.f,0.f,0.f};
    f4 acc[2][4];
    #pragma unroll
    for (int i = 0; i < 2; i++) for (int j = 0; j < 4; j++) acc[i][j] = zz;
    const half_t* ap = h2h + (long)(b0 + wr*32 + ln)*WD + lk*8;
    const half_t* bp = w3t + (long)(c0 + wc*64 + ln)*WD + lk*8;
    #pragma unroll
    for (int ks = 0; ks < 4; ks++) {
        h8 a0 = *(const h8*)(ap + ks*32);
        h8 a1 = *(const h8*)(ap + 16*WD + ks*32);
        #pragma unroll
        for (int bt = 0; bt < 4; bt++) {
            h8 bf = *(const h8*)(bp + bt*16*WD + ks*32);
            acc[0][bt] = MFMA(a0, bf, acc[0][bt]);
            acc[1][bt] = MFMA(a1, bf, acc[1][bt]);
        }
    }
    #pragma unroll
    for (int at = 0; at < 2; at++)
    #pragma unroll
    for (int bt = 0; bt < 4; bt++) {
        int col = c0 + wc*64 + bt*16 + ln;
        float bias = b3[col];
        #pragma unroll
        for (int r = 0; r < 4; r++) {
            int b = b0 + wr*32 + at*16 + lk*4 + r;
            x[(long)b*NCOL + col] = acc[at][bt][r] + bias;
        }
    }
}

// ---------------- transpose x fp32 [b][c][t] -> xt fp16 [b][t][c] AND xc fp16 [b][c][t] ----------------
__global__ __launch_bounds__(256) void k_tr2(const float* __restrict__ x, half_t* __restrict__ xt,
                                             half_t* __restrict__ xc){
    __shared__ half_t tl[WD*65];   // [c][t] pad 65
    int tid = threadIdx.x;
    int t0 = blockIdx.x * 64;
    long b = blockIdx.y;
    {
        int c = tid >> 1, th = tid & 1;
        const float* xp = x + b*NCOL + (long)c*TD + t0 + th*32;
        half_t reg[32];
        #pragma unroll
        for (int i = 0; i < 8; i++) {
            int t = t0 + th*32 + i*4;
            float4 v;
            if (t + 3 < TD) v = *(const float4*)(xp + i*4);
            else v = make_float4((t<TD)?xp[i*4]:0.f, (t+1<TD)?xp[i*4+1]:0.f,
                                 (t+2<TD)?xp[i*4+2]:0.f, (t+3<TD)?xp[i*4+3]:0.f);
            reg[i*4+0]=(half_t)v.x; reg[i*4+1]=(half_t)v.y;
            reg[i*4+2]=(half_t)v.z; reg[i*4+3]=(half_t)v.w;
        }
        half_t* dst = &tl[c*65 + th*32];
        #pragma unroll
        for (int i = 0; i < 32; i++) dst[i] = reg[i];
        half_t* op = xc + (b*WD + c)*TP + t0 + th*32;
        *(h8*)(op)    = *(h8*)(&reg[0]);
        *(h8*)(op+8)  = *(h8*)(&reg[8]);
        *(h8*)(op+16) = *(h8*)(&reg[16]);
        *(h8*)(op+24) = *(h8*)(&reg[24]);
    }
    __syncthreads();
    {
        int lane = tid & 63, w = tid >> 6;
        const half_t* src = &tl[w*32*65 + lane];
        h8 v[4];
        #pragma unroll
        for (int k2 = 0; k2 < 4; k2++)
            #pragma unroll
            for (int e = 0; e < 8; e++)
                v[k2][e] = src[(k2*8 + e)*65];
        half_t* op = xt + (b*TP + t0 + lane)*WD + w*32;
        *(h8*)(op) = v[0]; *(h8*)(op+8) = v[1]; *(h8*)(op+16) = v[2]; *(h8*)(op+24) = v[3];
    }
}

// ---------------- rfft MFMA from xc (fp16, K=t=320 zero-padded) ----------------
__global__ __launch_bounds__(256) void k_rfft(const half_t* __restrict__ xc, const half_t* __restrict__ Fth,
        half_t* __restrict__ S, int CB){
    int tid = threadIdx.x;
    int lane = tid & 63, w = tid >> 6;
    int ln = lane & 15, lk = lane >> 4;
    long r0 = (long)blockIdx.x*128 + w*32;
    f4 zz = {0.f,0.f,0.f,0.f};
    f4 acc[2][3];
    #pragma unroll
    for (int i = 0; i < 2; i++) for (int j = 0; j < 3; j++) acc[i][j] = zz;
    const half_t* ap = xc + r0*TP + lk*8;
    const half_t* fpB = Fth + ln*TP + lk*8;
    #pragma unroll
    for (int ks = 0; ks < 10; ks++) {
        h8 a0 = *(const h8*)(ap + ln*TP + ks*32);
        h8 a1 = *(const h8*)(ap + (16+ln)*TP + ks*32);
        #pragma unroll
        for (int jt = 0; jt < 3; jt++) {
            h8 bf = *(const h8*)(fpB + jt*16*TP + ks*32);
            acc[0][jt] = MFMA(a0, bf, acc[0][jt]);
            acc[1][jt] = MFMA(a1, bf, acc[1][jt]);
        }
    }
    #pragma unroll
    for (int at = 0; at < 2; at++)
    #pragma unroll
    for (int jt = 0; jt < 3; jt++) {
        int j = jt*16 + ln;
        int m = j >> 1, ri = j & 1;
        #pragma unroll
        for (int r = 0; r < 4; r++) {
            long row = r0 + at*16 + lk*4 + r;
            int b = (int)(row >> 7), c = (int)(row & 127);
            S[((long)m*CB + b)*256 + ri*128 + c] = (half_t)acc[at][jt][r];
        }
    }
}

// ---------------- mix MFMA: per mode, [CB x 256] @ [256 x 256] ----------------
__global__ __launch_bounds__(256) void k_mix(const half_t* __restrict__ S, const half_t* __restrict__ Wxh,
        half_t* __restrict__ Yh, int layer, int CB){
    int tid = threadIdx.x;
    int lane = tid & 63, w = tid >> 6;
    int wr = w >> 1, wc = w & 1;
    int ln = lane & 15, lk = lane >> 4;
    int m = blockIdx.z;
    int b0 = blockIdx.x * 64;
    int n0 = blockIdx.y * 128;
    f4 zz = {0.f,0.f,0.f,0.f};
    f4 acc[2][4];
    #pragma unroll
    for (int i = 0; i < 2; i++) for (int j = 0; j < 4; j++) acc[i][j] = zz;
    const half_t* ap = S + ((long)m*CB + b0 + wr*32 + ln)*256 + lk*8;
    const half_t* bp = Wxh + (((long)(layer*NM + m))*256 + n0 + wc*64 + ln)*256 + lk*8;
    #pragma unroll
    for (int ks = 0; ks < 8; ks++) {
        h8 a0 = *(const h8*)(ap + ks*32);
        h8 a1 = *(const h8*)(ap + 16*256 + ks*32);
        #pragma unroll
        for (int bt = 0; bt < 4; bt++) {
            h8 bf = *(const h8*)(bp + bt*16*256 + ks*32);
            acc[0][bt] = MFMA(a0, bf, acc[0][bt]);
            acc[1][bt] = MFMA(a1, bf, acc[1][bt]);
        }
    }
    const float inv = 1.0f / WSCALE;
    #pragma unroll
    for (int at = 0; at < 2; at++)
    #pragma unroll
    for (int bt = 0; bt < 4; bt++) {
        int n = n0 + wc*64 + bt*16 + ln;
        int o = n & 127, ri = n >> 7;
        #pragma unroll
        for (int r = 0; r < 4; r++) {
            int b = b0 + wr*32 + at*16 + lk*4 + r;
            Yh[((long)b*WD + o)*NJP + 2*m + ri] = (half_t)(acc[at][bt][r] * inv);
        }
    }
}

// ---------------- fused irfft + conv + gelu + residual (fp16 master, in-place xt, writes xc) ----------------
// Block owns (b, t-tile of 64, all o). GEMM K=192: A=[cwh|Yh] rows o, B=[xt|Gt] rows t.
// Residual read from xt (same t-tile -> no cross-block hazard). Pads t>=300 forced to 0.
__global__ __launch_bounds__(256) void k_fuse(const half_t* __restrict__ Yh, const half_t* __restrict__ Gt,
        const half_t* __restrict__ cwh, half_t* __restrict__ xt, const float* __restrict__ convb,
        half_t* __restrict__ xc, int layer){
    __shared__ float gl[64*133];   // [t][o] pad 133
    int tid = threadIdx.x;
    int lane = tid & 63, w = tid >> 6;
    int wo = w * 32;
    int ln = lane & 15, lk = lane >> 4;
    int t0 = blockIdx.x * 64;
    long b = blockIdx.y;
    f4 zz = {0.f,0.f,0.f,0.f};
    f4 acc[2][4];
    #pragma unroll
    for (int i = 0; i < 2; i++) for (int j = 0; j < 4; j++) acc[i][j] = zz;
    // conv region: K = c 0..127
    const half_t* ap = cwh + ((long)layer*WD + wo + ln)*WD + lk*8;
    const half_t* bp = xt + (b*TP + t0 + ln)*WD + lk*8;
    #pragma unroll
    for (int ks = 0; ks < 4; ks++) {
        h8 a0 = *(const h8*)(ap + ks*32);
        h8 a1 = *(const h8*)(ap + 16*WD + ks*32);
        #pragma unroll
        for (int bt = 0; bt < 4; bt++) {
            h8 bf = *(const h8*)(bp + bt*16*WD + ks*32);
            acc[0][bt] = MFMA(a0, bf, acc[0][bt]);
            acc[1][bt] = MFMA(a1, bf, acc[1][bt]);
        }
    }
    // irfft region: K = j 0..63 (Yh j>=48 finite garbage x Gt zeros -> 0)
    const half_t* ap2 = Yh + (b*WD + wo + ln)*NJP + lk*8;
    const half_t* bp2 = Gt + (long)(t0 + ln)*NJP + lk*8;
    #pragma unroll
    for (int ks = 0; ks < 2; ks++) {
        h8 a0 = *(const h8*)(ap2 + ks*32);
        h8 a1 = *(const h8*)(ap2 + 16*NJP + ks*32);
        #pragma unroll
        for (int bt = 0; bt < 4; bt++) {
            h8 bf = *(const h8*)(bp2 + bt*16*NJP + ks*32);
            acc[0][bt] = MFMA(a0, bf, acc[0][bt]);
            acc[1][bt] = MFMA(a1, bf, acc[1][bt]);
        }
    }
    // stage gelu(acc + bias) into LDS [t][o]
    #pragma unroll
    for (int at = 0; at < 2; at++) {
        int obase = wo + at*16 + lk*4;
        float cb0 = convb[layer*WD + obase];
        float cb1 = convb[layer*WD + obase + 1];
        float cb2 = convb[layer*WD + obase + 2];
        float cb3 = convb[layer*WD + obase + 3];
        #pragma unroll
        for (int bt = 0; bt < 4; bt++) {
            float* g = &gl[(bt*16 + ln)*133 + obase];
            g[0] = gelu_f(acc[at][bt][0] + cb0);
            g[1] = gelu_f(acc[at][bt][1] + cb1);
            g[2] = gelu_f(acc[at][bt][2] + cb2);
            g[3] = gelu_f(acc[at][bt][3] + cb3);
        }
    }
    __syncthreads();
    // phase A: add fp16 residual from xt (coalesced), zero pads
    {
        int tl_ = tid >> 2, c0 = (tid & 3)*32;
        int t = t0 + tl_;
        float* g = &gl[tl_*133 + c0];
        if (t < TD) {
            const half_t* xr = xt + (b*TP + t)*WD + c0;
            h8 v0 = *(const h8*)(xr);
            h8 v1 = *(const h8*)(xr + 8);
            h8 v2 = *(const h8*)(xr + 16);
            h8 v3 = *(const h8*)(xr + 24);
            #pragma unroll
            for (int i = 0; i < 8; i++) {
                g[i]    += (float)v0[i];
                g[8+i]  += (float)v1[i];
                g[16+i] += (float)v2[i];
                g[24+i] += (float)v3[i];
            }
        } else {
            #pragma unroll
            for (int i = 0; i < 32; i++) g[i] = 0.0f;
        }
    }
    __syncthreads();
    // phase B1: coalesced xt write
    {
        const float* gr = &gl[lane*133 + wo];
        h8 v[4];
        #pragma unroll
        for (int k2 = 0; k2 < 4; k2++)
            #pragma unroll
            for (int e = 0; e < 8; e++)
                v[k2][e] = (half_t)gr[k2*8 + e];
        half_t* op = xt + (b*TP + t0 + lane)*WD + wo;
        *(h8*)(op) = v[0]; *(h8*)(op+8) = v[1]; *(h8*)(op+16) = v[2]; *(h8*)(op+24) = v[3];
    }
    // phase B2: coalesced xc write (transposed via LDS)
    {
        int c = tid >> 1, th = tid & 1;
        half_t* op = xc + (b*WD + c)*TP + t0 + th*32;
        #pragma unroll
        for (int e = 0; e < 32; e += 8) {
            h8 v;
            #pragma unroll
            for (int i = 0; i < 8; i++)
                v[i] = (half_t)gl[(th*32 + e + i)*133 + c];
            *(h8*)(op + e) = v;
        }
    }
}

// ---------------- output projection MFMA ----------------
__global__ __launch_bounds__(256) void k_out(const half_t* __restrict__ xt, const half_t* __restrict__ w1h,
        const float* __restrict__ b1, const float* __restrict__ w2, const float* __restrict__ b2,
        float* __restrict__ out){
    __shared__ float gl[64*68];   // [t][o] padded
    __shared__ float w2l[192];
    int tid = threadIdx.x;
    int lane = tid & 63, w = tid >> 6;
    int mo = (w >> 1)*32, mt = (w & 1)*32;
    int ln = lane & 15, lk = lane >> 4;
    int t0 = blockIdx.x * 64;
    long b = blockIdx.y;
    f4 zz = {0.f,0.f,0.f,0.f};
    f4 acc[2][2];
    #pragma unroll
    for (int i = 0; i < 2; i++) for (int j = 0; j < 2; j++) acc[i][j] = zz;
    const half_t* ap = w1h + (long)(mo + ln)*WD + lk*8;
    const half_t* bp = xt + (b*TP + t0 + mt + ln)*WD + lk*8;
    #pragma unroll
    for (int ks = 0; ks < 4; ks++) {
        h8 a0 = *(const h8*)(ap + ks*32);
        h8 a1 = *(const h8*)(ap + 16*WD + ks*32);
        h8 b0f = *(const h8*)(bp + ks*32);
        h8 b1f = *(const h8*)(bp + 16*WD + ks*32);
        acc[0][0] = MFMA(a0, b0f, acc[0][0]);
        acc[0][1] = MFMA(a0, b1f, acc[0][1]);
        acc[1][0] = MFMA(a1, b0f, acc[1][0]);
        acc[1][1] = MFMA(a1, b1f, acc[1][1]);
    }
    if (tid < 192) w2l[tid] = w2[tid];
    #pragma unroll
    for (int at = 0; at < 2; at++)
    #pragma unroll
    for (int bt = 0; bt < 2; bt++) {
        int tl = mt + bt*16 + ln;
        int obase = mo + at*16 + lk*4;
        #pragma unroll
        for (int r = 0; r < 4; r++) {
            int o = obase + r;
            gl[tl*68 + o] = gelu_f(acc[at][bt][r] + b1[o]);
        }
    }
    __syncthreads();
    int t = tid & 63, q = tid >> 6;
    int tg = t0 + t;
    if (q < 3 && tg < TD) {
        float s = b2[q];
        const float* gr = &gl[t*68];
        const float* wr = &w2l[q*64];
        #pragma unroll
        for (int o = 0; o < 64; o += 4) {
            s += wr[o]*gr[o] + wr[o+1]*gr[o+1] + wr[o+2]*gr[o+2] + wr[o+3]*gr[o+3];
        }
        out[((long)b*TD + tg)*3 + q] = s;
    }
}

extern "C" void kernel_launch(void* const* d_in, const int* in_sizes, int n_in,
                              void* d_out, int out_size, void* d_ws, size_t ws_size,
                              hipStream_t stream) {
    const float* params = (const float*)d_in[0];
    const float* enc_w1 = (const float*)d_in[1];
    const float* enc_b1 = (const float*)d_in[2];
    const float* enc_w2 = (const float*)d_in[3];
    const float* enc_b2 = (const float*)d_in[4];
    const float* enc_w3 = (const float*)d_in[5];
    const float* enc_b3 = (const float*)d_in[6];
    const float* spec_wr = (const float*)d_in[7];
    const float* spec_wi = (const float*)d_in[8];
    const float* conv_w  = (const float*)d_in[9];
    const float* conv_b  = (const float*)d_in[10];
    const float* out_w1  = (const float*)d_in[11];
    const float* out_b1  = (const float*)d_in[12];
    const float* out_w2  = (const float*)d_in[13];
    const float* out_b2  = (const float*)d_in[14];
    float* outp = (float*)d_out;

    const long szWxh = (long)NL*NM*256*256*2;
    const long szW3t = (long)NCOL*WD*2;
    const long szCwh = (long)NL*WD*WD*2;
    const long szW1h = (long)64*WD*2;
    const long szFth = (long)NJ*TP*2;
    const long szGt  = (long)TP*NJP*2;
    const long fixedB = szWxh + szW3t + szCwh + szW1h + szFth + szGt;
    // per-sample bytes: x(fp32, enc only) + xt + xc + S + Yh + h1 + h2h
    const long perCB = (long)NCOL*4 + 2L*(long)TP*WD*2 + (long)NM*256*2 + (long)WD*NJP*2 + WD*4 + WD*2;

    // CB=512: steady-state layer working set (~136 MB) fits the 256 MB Infinity Cache
    long CB = 512;
    while (CB > 64 && fixedB + CB*perCB > (long)ws_size) CB >>= 1;
    int nchunk = (int)(NB / CB);

    char* p = (char*)d_ws;
    half_t* Wxh = (half_t*)p; p += szWxh;
    half_t* w3t = (half_t*)p; p += szW3t;
    half_t* cwh = (half_t*)p; p += szCwh;
    half_t* w1h = (half_t*)p; p += szW1h;
    half_t* Fth = (half_t*)p; p += szFth;
    half_t* Gt  = (half_t*)p; p += szGt;
    float*  x   = (float*)p;  p += CB*(long)NCOL*4;
    half_t* xt  = (half_t*)p; p += CB*(long)TP*WD*2;
    half_t* xc  = (half_t*)p; p += CB*(long)TP*WD*2;
    half_t* S   = (half_t*)p; p += CB*(long)NM*256*2;
    half_t* Yh  = (half_t*)p; p += CB*(long)WD*NJP*2;
    float*  h1  = (float*)p;  p += CB*(long)WD*4;
    half_t* h2h = (half_t*)p; p += CB*(long)WD*2;

    k_tables<<<80, 256, 0, stream>>>(Fth, Gt);
    k_wx<<<36864, 256, 0, stream>>>(spec_wr, spec_wi, Wxh);
    k_w3t<<<19200, 256, 0, stream>>>(enc_w3, w3t);
    k_cwh<<<384, 256, 0, stream>>>(conv_w, cwh);
    k_w1h<<<32, 256, 0, stream>>>(out_w1, w1h);

    for (int ch = 0; ch < nchunk; ch++) {
        const float* pch = params + (long)ch*CB*5;
        float* outch = outp + (long)ch*CB*TD*3;
        k_enc1<<<(int)(CB*WD/256), 256, 0, stream>>>(pch, enc_w1, enc_b1, h1);
        k_enc2<<<(int)(CB*WD/256), 256, 0, stream>>>(h1, enc_w2, enc_b2, h2h);
        k_enc3<<<dim3(NCOL/128, (int)(CB/64)), 256, 0, stream>>>(h2h, w3t, enc_b3, x);
        k_tr2<<<dim3(TP/64, (int)CB), 256, 0, stream>>>(x, xt, xc);
        for (int l = 0; l < NL; l++) {
            k_rfft<<<(int)CB, 256, 0, stream>>>(xc, Fth, S, (int)CB);
            k_mix<<<dim3((int)(CB/64), 2, NM), 256, 0, stream>>>(S, Wxh, Yh, l, (int)CB);
            k_fuse<<<dim3(TP/64, (int)CB), 256, 0, stream>>>(Yh, Gt, cwh, xt, conv_b, xc, l);
        }
        k_out<<<dim3(TP/64, (int)CB), 256, 0, stream>>>(xt, w1h, out_b1, out_w2, out_b2, outch);
    }
}

// Round 7
// 3371.531 us; speedup vs baseline: 1.5043x; 1.0674x over previous
//
#include <hip/hip_runtime.h>
#include <math.h>

#define NB 2048
#define WD 128
#define TD 300
#define TP 320
#define NM 24
#define NJ 48
#define NJP 64
#define NL 6
#define NCOL 38400
#define WSCALE 1024.0f

typedef _Float16 half_t;
typedef _Float16 h8 __attribute__((ext_vector_type(8)));
typedef float f4 __attribute__((ext_vector_type(4)));

#define MFMA(a,b,c) __builtin_amdgcn_mfma_f32_16x16x32_f16(a,b,c,0,0,0)

__device__ __forceinline__ float gelu_f(float v){
    return 0.5f * v * (1.0f + erff(v * 0.70710678118654752f));
}

// ---------------- DFT basis tables (fp16) ----------------
__global__ __launch_bounds__(256) void k_tables(half_t* __restrict__ Fth, half_t* __restrict__ Gt){
    int idx = blockIdx.x*256 + threadIdx.x;
    const float w0 = 6.28318530717958647692f / 300.0f;
    if (idx < NJ*TP) {
        int j = idx / TP, t = idx - j*TP;
        int m = j >> 1;
        float v = 0.0f;
        if (t < TD) {
            int r = (m*t) % TD;
            float ang = (float)r * w0;
            v = (j & 1) ? -sinf(ang) : cosf(ang);
        }
        Fth[idx] = (half_t)v;
    }
    if (idx < TP*NJP) {
        int t = idx / NJP, j = idx - t*NJP;
        float v = 0.0f;
        if (j < NJ) {
            int m = j >> 1;
            int r = (m * (t % TD)) % TD;
            float ang = (float)r * w0;
            float s = (m == 0) ? (1.0f/300.0f) : (2.0f/300.0f);
            if (j & 1) v = (m == 0) ? 0.0f : -s*sinf(ang);
            else       v = s*cosf(ang);
        }
        Gt[idx] = (half_t)v;
    }
}

// ---------------- expanded complex weights ----------------
__global__ __launch_bounds__(256) void k_wx(const float* __restrict__ wr, const float* __restrict__ wi,
                                            half_t* __restrict__ Wxh){
    long idx = (long)blockIdx.x*256 + threadIdx.x;
    if (idx >= (long)NL*NM*256*256) return;
    int k = (int)(idx & 255), n = (int)((idx >> 8) & 255);
    int lm = (int)(idx >> 16);
    int l = lm / NM, m = lm - l*NM;
    int i = k & 127, o = n & 127;
    long src = (((long)(l*WD + i))*WD + o)*NM + m;
    float v;
    if (n < 128) v = (k < 128) ? wr[src] : -wi[src];
    else         v = (k < 128) ? wi[src] :  wr[src];
    Wxh[idx] = (half_t)(v * WSCALE);
}

// w3t2[(t*WD + c)*WD + k] = w3[k][c*TD + t]
__global__ __launch_bounds__(256) void k_w3t2(const float* __restrict__ w3, half_t* __restrict__ w3t2){
    long idx = (long)blockIdx.x*256 + threadIdx.x;
    if (idx >= (long)TD*WD*WD) return;
    int k = (int)(idx & 127);
    long rest = idx >> 7;
    int c = (int)(rest & 127);
    int t = (int)(rest >> 7);
    w3t2[idx] = (half_t)w3[(long)k*NCOL + c*TD + t];
}

__global__ __launch_bounds__(256) void k_cwh(const float* __restrict__ cw, half_t* __restrict__ cwh){
    int idx = blockIdx.x*256 + threadIdx.x;
    if (idx >= NL*WD*WD) return;
    cwh[idx] = (half_t)cw[idx];
}

__global__ __launch_bounds__(256) void k_w1h(const float* __restrict__ w1, half_t* __restrict__ w1h){
    int idx = blockIdx.x*256 + threadIdx.x;
    if (idx >= 64*WD) return;
    w1h[idx] = (half_t)w1[idx];
}

// ---------------- encoder ----------------
__global__ __launch_bounds__(256) void k_enc1(const float* __restrict__ p, const float* __restrict__ w1,
                                              const float* __restrict__ b1, float* __restrict__ h1){
    int idx = blockIdx.x*256 + threadIdx.x;
    int b = idx >> 7, k = idx & 127;
    float acc = b1[k];
    #pragma unroll
    for (int j = 0; j < 5; j++) acc += p[b*5+j] * w1[j*WD+k];
    h1[idx] = gelu_f(acc);
}

__global__ __launch_bounds__(256) void k_enc2(const float* __restrict__ h1, const float* __restrict__ w2,
                                              const float* __restrict__ b2, half_t* __restrict__ h2h){
    int idx = blockIdx.x*256 + threadIdx.x;
    int b = idx >> 7, k = idx & 127;
    const float* row = h1 + b*WD;
    float acc = b2[k];
    for (int j = 0; j < WD; j += 4) {
        float4 h4 = *(const float4*)(row + j);
        acc += h4.x * w2[(j+0)*WD+k] + h4.y * w2[(j+1)*WD+k]
             + h4.z * w2[(j+2)*WD+k] + h4.w * w2[(j+3)*WD+k];
    }
    h2h[idx] = (half_t)gelu_f(acc);
}

// ---------------- enc3 MFMA: per-t block [64 b][128 c], writes xt fp16 directly ----------------
__global__ __launch_bounds__(256) void k_enc3(const half_t* __restrict__ h2h, const half_t* __restrict__ w3t2,
        const float* __restrict__ b3, half_t* __restrict__ xt){
    int tid = threadIdx.x;
    int t = blockIdx.x;
    int b0 = blockIdx.y * 64;
    if (t >= TD) {   // zero pad rows
        int bb = tid >> 2, cg = (tid & 3) * 32;
        half_t* op = xt + ((long)(b0 + bb)*TP + t)*WD + cg;
        uint4 z = make_uint4(0,0,0,0);
        *(uint4*)(op) = z; *(uint4*)(op + 16) = z;
        return;
    }
    int lane = tid & 63, w = tid >> 6;
    int wr = w >> 1, wc = w & 1;
    int ln = lane & 15, lk = lane >> 4;
    f4 zz = {0.f,0.f,0.f,0.f};
    f4 acc[2][4];
    #pragma unroll
    for (int i = 0; i < 2; i++) for (int j = 0; j < 4; j++) acc[i][j] = zz;
    const half_t* ap = h2h + (long)(b0 + wr*32 + ln)*WD + lk*8;
    const half_t* bp = w3t2 + ((long)t*WD + wc*64 + ln)*WD + lk*8;
    #pragma unroll
    for (int ks = 0; ks < 4; ks++) {
        h8 a0 = *(const h8*)(ap + ks*32);
        h8 a1 = *(const h8*)(ap + 16*WD + ks*32);
        #pragma unroll
        for (int bt = 0; bt < 4; bt++) {
            h8 bf = *(const h8*)(bp + bt*16*WD + ks*32);
            acc[0][bt] = MFMA(a0, bf, acc[0][bt]);
            acc[1][bt] = MFMA(a1, bf, acc[1][bt]);
        }
    }
    #pragma unroll
    for (int at = 0; at < 2; at++)
    #pragma unroll
    for (int bt = 0; bt < 4; bt++) {
        int c = wc*64 + bt*16 + ln;
        float bias = b3[c*TD + t];
        #pragma unroll
        for (int r = 0; r < 4; r++) {
            int b = b0 + wr*32 + at*16 + lk*4 + r;
            xt[((long)b*TP + t)*WD + c] = (half_t)(acc[at][bt][r] + bias);
        }
    }
}

// ---------------- transpose xt [b][t][c] -> xc [b][c][t], fp16, LDS staged ----------------
__global__ __launch_bounds__(256) void k_trh(const half_t* __restrict__ xt, half_t* __restrict__ xc){
    __shared__ half_t tl[64*136];   // [t][c pad 136]
    int tid = threadIdx.x;
    int t0 = blockIdx.x * 64;
    long b = blockIdx.y;
    {
        int tr = tid >> 2, q = (tid & 3) * 32;
        const half_t* ip = xt + (b*TP + t0 + tr)*WD + q;
        h8 v0 = *(const h8*)(ip);
        h8 v1 = *(const h8*)(ip + 8);
        h8 v2 = *(const h8*)(ip + 16);
        h8 v3 = *(const h8*)(ip + 24);
        half_t* dst = &tl[tr*136 + q];
        *(h8*)(dst) = v0; *(h8*)(dst+8) = v1; *(h8*)(dst+16) = v2; *(h8*)(dst+24) = v3;
    }
    __syncthreads();
    {
        int c = tid >> 1, th = tid & 1;
        const half_t* src = &tl[th*32*136 + c];
        h8 o[4];
        #pragma unroll
        for (int k2 = 0; k2 < 4; k2++)
            #pragma unroll
            for (int e = 0; e < 8; e++)
                o[k2][e] = src[(k2*8 + e)*136];
        half_t* op = xc + (b*WD + c)*TP + t0 + th*32;
        *(h8*)(op) = o[0]; *(h8*)(op+8) = o[1]; *(h8*)(op+16) = o[2]; *(h8*)(op+24) = o[3];
    }
}

// ---------------- rfft MFMA from xc (fp16, K=t=320 zero-padded) ----------------
__global__ __launch_bounds__(256) void k_rfft(const half_t* __restrict__ xc, const half_t* __restrict__ Fth,
        half_t* __restrict__ S, int CB){
    int tid = threadIdx.x;
    int lane = tid & 63, w = tid >> 6;
    int ln = lane & 15, lk = lane >> 4;
    long r0 = (long)blockIdx.x*128 + w*32;
    f4 zz = {0.f,0.f,0.f,0.f};
    f4 acc[2][3];
    #pragma unroll
    for (int i = 0; i < 2; i++) for (int j = 0; j < 3; j++) acc[i][j] = zz;
    const half_t* ap = xc + r0*TP + lk*8;
    const half_t* fpB = Fth + ln*TP + lk*8;
    #pragma unroll
    for (int ks = 0; ks < 10; ks++) {
        h8 a0 = *(const h8*)(ap + ln*TP + ks*32);
        h8 a1 = *(const h8*)(ap + (16+ln)*TP + ks*32);
        #pragma unroll
        for (int jt = 0; jt < 3; jt++) {
            h8 bf = *(const h8*)(fpB + jt*16*TP + ks*32);
            acc[0][jt] = MFMA(a0, bf, acc[0][jt]);
            acc[1][jt] = MFMA(a1, bf, acc[1][jt]);
        }
    }
    #pragma unroll
    for (int at = 0; at < 2; at++)
    #pragma unroll
    for (int jt = 0; jt < 3; jt++) {
        int j = jt*16 + ln;
        int m = j >> 1, ri = j & 1;
        #pragma unroll
        for (int r = 0; r < 4; r++) {
            long row = r0 + at*16 + lk*4 + r;
            int b = (int)(row >> 7), c = (int)(row & 127);
            S[((long)m*CB + b)*256 + ri*128 + c] = (half_t)acc[at][jt][r];
        }
    }
}

// ---------------- mix MFMA: per mode, [CB x 256] @ [256 x 256] ----------------
__global__ __launch_bounds__(256) void k_mix(const half_t* __restrict__ S, const half_t* __restrict__ Wxh,
        half_t* __restrict__ Yh, int layer, int CB){
    int tid = threadIdx.x;
    int lane = tid & 63, w = tid >> 6;
    int wr = w >> 1, wc = w & 1;
    int ln = lane & 15, lk = lane >> 4;
    int m = blockIdx.z;
    int b0 = blockIdx.x * 64;
    int n0 = blockIdx.y * 128;
    f4 zz = {0.f,0.f,0.f,0.f};
    f4 acc[2][4];
    #pragma unroll
    for (int i = 0; i < 2; i++) for (int j = 0; j < 4; j++) acc[i][j] = zz;
    const half_t* ap = S + ((long)m*CB + b0 + wr*32 + ln)*256 + lk*8;
    const half_t* bp = Wxh + (((long)(layer*NM + m))*256 + n0 + wc*64 + ln)*256 + lk*8;
    #pragma unroll
    for (int ks = 0; ks < 8; ks++) {
        h8 a0 = *(const h8*)(ap + ks*32);
        h8 a1 = *(const h8*)(ap + 16*256 + ks*32);
        #pragma unroll
        for (int bt = 0; bt < 4; bt++) {
            h8 bf = *(const h8*)(bp + bt*16*256 + ks*32);
            acc[0][bt] = MFMA(a0, bf, acc[0][bt]);
            acc[1][bt] = MFMA(a1, bf, acc[1][bt]);
        }
    }
    const float inv = 1.0f / WSCALE;
    #pragma unroll
    for (int at = 0; at < 2; at++)
    #pragma unroll
    for (int bt = 0; bt < 4; bt++) {
        int n = n0 + wc*64 + bt*16 + ln;
        int o = n & 127, ri = n >> 7;
        #pragma unroll
        for (int r = 0; r < 4; r++) {
            int b = b0 + wr*32 + at*16 + lk*4 + r;
            Yh[((long)b*WD + o)*NJP + 2*m + ri] = (half_t)(acc[at][bt][r] * inv);
        }
    }
}

// ---------------- fused irfft + conv + gelu + residual (+ output projection on last layer) ----------------
__global__ __launch_bounds__(256) void k_fuse(const half_t* __restrict__ Yh, const half_t* __restrict__ Gt,
        const half_t* __restrict__ cwh, half_t* __restrict__ xt, const float* __restrict__ convb,
        half_t* __restrict__ xc, int layer, int last,
        const half_t* __restrict__ w1h, const float* __restrict__ ob1,
        const float* __restrict__ ow2, const float* __restrict__ ob2, float* __restrict__ out){
    __shared__ float gl[64*133];   // [t][o] pad 133
    __shared__ float w2l[192];
    int tid = threadIdx.x;
    int lane = tid & 63, w = tid >> 6;
    int wo = w * 32;
    int ln = lane & 15, lk = lane >> 4;
    int t0 = blockIdx.x * 64;
    long b = blockIdx.y;
    f4 zz = {0.f,0.f,0.f,0.f};
    f4 acc[2][4];
    #pragma unroll
    for (int i = 0; i < 2; i++) for (int j = 0; j < 4; j++) acc[i][j] = zz;
    // conv region: K = c 0..127
    const half_t* ap = cwh + ((long)layer*WD + wo + ln)*WD + lk*8;
    const half_t* bp = xt + (b*TP + t0 + ln)*WD + lk*8;
    #pragma unroll
    for (int ks = 0; ks < 4; ks++) {
        h8 a0 = *(const h8*)(ap + ks*32);
        h8 a1 = *(const h8*)(ap + 16*WD + ks*32);
        #pragma unroll
        for (int bt = 0; bt < 4; bt++) {
            h8 bf = *(const h8*)(bp + bt*16*WD + ks*32);
            acc[0][bt] = MFMA(a0, bf, acc[0][bt]);
            acc[1][bt] = MFMA(a1, bf, acc[1][bt]);
        }
    }
    // irfft region: K = j 0..63 (Yh j>=48 finite garbage x Gt zeros -> 0)
    const half_t* ap2 = Yh + (b*WD + wo + ln)*NJP + lk*8;
    const half_t* bp2 = Gt + (long)(t0 + ln)*NJP + lk*8;
    #pragma unroll
    for (int ks = 0; ks < 2; ks++) {
        h8 a0 = *(const h8*)(ap2 + ks*32);
        h8 a1 = *(const h8*)(ap2 + 16*NJP + ks*32);
        #pragma unroll
        for (int bt = 0; bt < 4; bt++) {
            h8 bf = *(const h8*)(bp2 + bt*16*NJP + ks*32);
            acc[0][bt] = MFMA(a0, bf, acc[0][bt]);
            acc[1][bt] = MFMA(a1, bf, acc[1][bt]);
        }
    }
    // stage gelu(acc + bias) into LDS [t][o]
    #pragma unroll
    for (int at = 0; at < 2; at++) {
        int obase = wo + at*16 + lk*4;
        float cb0 = convb[layer*WD + obase];
        float cb1 = convb[layer*WD + obase + 1];
        float cb2 = convb[layer*WD + obase + 2];
        float cb3 = convb[layer*WD + obase + 3];
        #pragma unroll
        for (int bt = 0; bt < 4; bt++) {
            float* g = &gl[(bt*16 + ln)*133 + obase];
            g[0] = gelu_f(acc[at][bt][0] + cb0);
            g[1] = gelu_f(acc[at][bt][1] + cb1);
            g[2] = gelu_f(acc[at][bt][2] + cb2);
            g[3] = gelu_f(acc[at][bt][3] + cb3);
        }
    }
    if (last && tid < 192) w2l[tid] = ow2[tid];
    __syncthreads();
    // phase A: add fp16 residual from xt; lane = t-row, wave covers 32 c (bank-free, matches B1)
    {
        int t = t0 + lane;
        float* g = &gl[lane*133 + wo];
        if (t < TD) {
            const half_t* xr = xt + (b*TP + t)*WD + wo;
            h8 v0 = *(const h8*)(xr);
            h8 v1 = *(const h8*)(xr + 8);
            h8 v2 = *(const h8*)(xr + 16);
            h8 v3 = *(const h8*)(xr + 24);
            #pragma unroll
            for (int i = 0; i < 8; i++) {
                g[i]    += (float)v0[i];
                g[8+i]  += (float)v1[i];
                g[16+i] += (float)v2[i];
                g[24+i] += (float)v3[i];
            }
        } else {
            #pragma unroll
            for (int i = 0; i < 32; i++) g[i] = 0.0f;
        }
    }
    __syncthreads();
    if (!last) {
        // phase B1: coalesced xt write
        {
            const float* gr = &gl[lane*133 + wo];
            h8 v[4];
            #pragma unroll
            for (int k2 = 0; k2 < 4; k2++)
                #pragma unroll
                for (int e = 0; e < 8; e++)
                    v[k2][e] = (half_t)gr[k2*8 + e];
            half_t* op = xt + (b*TP + t0 + lane)*WD + wo;
            *(h8*)(op) = v[0]; *(h8*)(op+8) = v[1]; *(h8*)(op+16) = v[2]; *(h8*)(op+24) = v[3];
        }
        // phase B2: coalesced xc write (transposed)
        {
            int c = tid >> 1, th = tid & 1;
            half_t* op = xc + (b*WD + c)*TP + t0 + th*32;
            #pragma unroll
            for (int e = 0; e < 32; e += 8) {
                h8 v;
                #pragma unroll
                for (int i = 0; i < 8; i++)
                    v[i] = (half_t)gl[(th*32 + e + i)*133 + c];
                *(h8*)(op + e) = v;
            }
        }
    } else {
        // output projection: A = w1h [64 o2][128 c], B = gl rows t (fp32 -> fp16)
        int mo = (w >> 1)*32, mt = (w & 1)*32;
        f4 oacc[2][2];
        #pragma unroll
        for (int i = 0; i < 2; i++) for (int j = 0; j < 2; j++) oacc[i][j] = zz;
        const half_t* wap = w1h + (long)(mo + ln)*WD + lk*8;
        #pragma unroll
        for (int ks = 0; ks < 4; ks++) {
            h8 a0 = *(const h8*)(wap + ks*32);
            h8 a1 = *(const h8*)(wap + 16*WD + ks*32);
            h8 b0f, b1f;
            const float* g0 = &gl[(mt + ln)*133 + ks*32 + lk*8];
            const float* g1 = &gl[(mt + 16 + ln)*133 + ks*32 + lk*8];
            #pragma unroll
            for (int e = 0; e < 8; e++) { b0f[e] = (half_t)g0[e]; b1f[e] = (half_t)g1[e]; }
            oacc[0][0] = MFMA(a0, b0f, oacc[0][0]);
            oacc[0][1] = MFMA(a0, b1f, oacc[0][1]);
            oacc[1][0] = MFMA(a1, b0f, oacc[1][0]);
            oacc[1][1] = MFMA(a1, b1f, oacc[1][1]);
        }
        __syncthreads();   // all gl (x_new) reads done
        #pragma unroll
        for (int at = 0; at < 2; at++)
        #pragma unroll
        for (int bt = 0; bt < 2; bt++) {
            int tl = mt + bt*16 + ln;
            int obase = mo + at*16 + lk*4;
            #pragma unroll
            for (int r = 0; r < 4; r++) {
                int o = obase + r;
                gl[tl*68 + o] = gelu_f(oacc[at][bt][r] + ob1[o]);
            }
        }
        __syncthreads();
        int tq = tid & 63, qq = tid >> 6;
        int tg = t0 + tq;
        if (qq < 3 && tg < TD) {
            float s = ob2[qq];
            const float* gr = &gl[tq*68];
            const float* wr2 = &w2l[qq*64];
            #pragma unroll
            for (int o = 0; o < 64; o += 4) {
                s += wr2[o]*gr[o] + wr2[o+1]*gr[o+1] + wr2[o+2]*gr[o+2] + wr2[o+3]*gr[o+3];
            }
            out[((long)b*TD + tg)*3 + qq] = s;
        }
    }
}

extern "C" void kernel_launch(void* const* d_in, const int* in_sizes, int n_in,
                              void* d_out, int out_size, void* d_ws, size_t ws_size,
                              hipStream_t stream) {
    const float* params = (const float*)d_in[0];
    const float* enc_w1 = (const float*)d_in[1];
    const float* enc_b1 = (const float*)d_in[2];
    const float* enc_w2 = (const float*)d_in[3];
    const float* enc_b2 = (const float*)d_in[4];
    const float* enc_w3 = (const float*)d_in[5];
    const float* enc_b3 = (const float*)d_in[6];
    const float* spec_wr = (const float*)d_in[7];
    const float* spec_wi = (const float*)d_in[8];
    const float* conv_w  = (const float*)d_in[9];
    const float* conv_b  = (const float*)d_in[10];
    const float* out_w1  = (const float*)d_in[11];
    const float* out_b1  = (const float*)d_in[12];
    const float* out_w2  = (const float*)d_in[13];
    const float* out_b2  = (const float*)d_in[14];
    float* outp = (float*)d_out;

    const long szWxh = (long)NL*NM*256*256*2;   // 18,874,368
    const long szW3t = (long)TD*WD*WD*2;        //  9,830,400
    const long szCwh = (long)NL*WD*WD*2;
    const long szW1h = (long)64*WD*2;
    const long szFth = (long)NJ*TP*2;
    const long szGt  = (long)TP*NJP*2;
    const long fixedB = szWxh + szW3t + szCwh + szW1h + szFth + szGt;
    // per-sample bytes: xt + xc + S + Yh + h1 + h2h
    const long perCB = 2L*(long)TP*WD*2 + (long)NM*256*2 + (long)WD*NJP*2 + WD*4 + WD*2;

    // CB=512: chunk working set ~128 MB, comfortably inside the 256 MB Infinity Cache
    long CB = 512;
    while (CB > 64 && fixedB + CB*perCB > (long)ws_size) CB >>= 1;
    int nchunk = (int)(NB / CB);

    char* p = (char*)d_ws;
    half_t* Wxh  = (half_t*)p; p += szWxh;
    half_t* w3t2 = (half_t*)p; p += szW3t;
    half_t* cwh  = (half_t*)p; p += szCwh;
    half_t* w1h  = (half_t*)p; p += szW1h;
    half_t* Fth  = (half_t*)p; p += szFth;
    half_t* Gt   = (half_t*)p; p += szGt;
    half_t* xt   = (half_t*)p; p += CB*(long)TP*WD*2;
    half_t* xc   = (half_t*)p; p += CB*(long)TP*WD*2;
    half_t* S    = (half_t*)p; p += CB*(long)NM*256*2;
    half_t* Yh   = (half_t*)p; p += CB*(long)WD*NJP*2;
    float*  h1   = (float*)p;  p += CB*(long)WD*4;
    half_t* h2h  = (half_t*)p; p += CB*(long)WD*2;

    k_tables<<<80, 256, 0, stream>>>(Fth, Gt);
    k_wx<<<36864, 256, 0, stream>>>(spec_wr, spec_wi, Wxh);
    k_w3t2<<<19200, 256, 0, stream>>>(enc_w3, w3t2);
    k_cwh<<<384, 256, 0, stream>>>(conv_w, cwh);
    k_w1h<<<32, 256, 0, stream>>>(out_w1, w1h);

    for (int ch = 0; ch < nchunk; ch++) {
        const float* pch = params + (long)ch*CB*5;
        float* outch = outp + (long)ch*CB*TD*3;
        k_enc1<<<(int)(CB*WD/256), 256, 0, stream>>>(pch, enc_w1, enc_b1, h1);
        k_enc2<<<(int)(CB*WD/256), 256, 0, stream>>>(h1, enc_w2, enc_b2, h2h);
        k_enc3<<<dim3(TP, (int)(CB/64)), 256, 0, stream>>>(h2h, w3t2, enc_b3, xt);
        k_trh<<<dim3(TP/64, (int)CB), 256, 0, stream>>>(xt, xc);
        for (int l = 0; l < NL; l++) {
            int last = (l == NL-1) ? 1 : 0;
            k_rfft<<<(int)CB, 256, 0, stream>>>(xc, Fth, S, (int)CB);
            k_mix<<<dim3((int)(CB/64), 2, NM), 256, 0, stream>>>(S, Wxh, Yh, l, (int)CB);
            k_fuse<<<dim3(TP/64, (int)CB), 256, 0, stream>>>(Yh, Gt, cwh, xt, conv_b, xc, l, last,
                                                             w1h, out_b1, out_w2, out_b2, outch);
        }
    }
}